// Round 3
// baseline (793.467 us; speedup 1.0000x reference)
//
#include <hip/hip_runtime.h>
#include <math.h>

#define TOK   8192
#define DD    1024
#define EE    8
#define HH    4096
#define MAXROWS 9216   // 8192 + 8*128 headroom, = 72 tiles * 128
#define MAXMT 72

typedef unsigned short u16;
typedef unsigned int   u32;
typedef __bf16 bf16x8 __attribute__((ext_vector_type(8)));
typedef float  f32x16 __attribute__((ext_vector_type(16)));

__device__ __forceinline__ u16 f2bf(float f) {
  union { float f; u32 u; } v; v.f = f;
  u32 r = v.u + 0x7fffu + ((v.u >> 16) & 1u);   // RNE, finite inputs only
  return (u16)(r >> 16);
}

__device__ __forceinline__ void gload16(const void* g, void* l) {
  __builtin_amdgcn_global_load_lds(
      (const __attribute__((address_space(1))) void*)g,
      (__attribute__((address_space(3))) void*)l, 16, 0, 0);
}

// ---------------- init: rowmap=-1, zero atomic counters ----------------
__global__ void k_init(int* rowmap, int* counts, int* fill) {
  int i = blockIdx.x * 256 + threadIdx.x;
  if (i < MAXROWS) rowmap[i] = -1;
  if (blockIdx.x == 0 && threadIdx.x < EE) { counts[threadIdx.x] = 0; fill[threadIdx.x] = 0; }
}

// ---------------- routing (1 wave/token) + fused x->bf16 conversion ----------------
__global__ __launch_bounds__(256)
void k_route(const float* __restrict__ x, const float* __restrict__ Wr,
             const float* __restrict__ br, int* __restrict__ eid,
             int* __restrict__ counts, u16* __restrict__ xb) {
  int t = blockIdx.x * 4 + (threadIdx.x >> 6);
  int lt = threadIdx.x & 63;
  const float4* xr = (const float4*)(x + (size_t)t * DD);
  u16* xbr = xb + (size_t)t * DD;
  const float4* wrp = (const float4*)Wr;
  float acc[EE];
  #pragma unroll
  for (int e = 0; e < EE; ++e) acc[e] = 0.f;
  #pragma unroll
  for (int i = 0; i < 4; ++i) {
    int d4 = lt + 64 * i;          // float4 index; d = 4*d4
    float4 v = xr[d4];
    u32 p0 = (u32)f2bf(v.x) | ((u32)f2bf(v.y) << 16);
    u32 p1 = (u32)f2bf(v.z) | ((u32)f2bf(v.w) << 16);
    ((uint2*)xbr)[d4] = make_uint2(p0, p1);
    float vv[4] = { v.x, v.y, v.z, v.w };
    #pragma unroll
    for (int dd = 0; dd < 4; ++dd) {
      float xv = vv[dd];
      float4 a = wrp[(size_t)(d4 * 4 + dd) * 2];
      float4 b = wrp[(size_t)(d4 * 4 + dd) * 2 + 1];
      acc[0] += xv * a.x; acc[1] += xv * a.y; acc[2] += xv * a.z; acc[3] += xv * a.w;
      acc[4] += xv * b.x; acc[5] += xv * b.y; acc[6] += xv * b.z; acc[7] += xv * b.w;
    }
  }
  #pragma unroll
  for (int e = 0; e < EE; ++e)
    #pragma unroll
    for (int off = 32; off > 0; off >>= 1) acc[e] += __shfl_down(acc[e], off);
  if (lt == 0) {
    float best = -1e30f; int be = 0;
    #pragma unroll
    for (int e = 0; e < EE; ++e) {
      float v = acc[e] + br[e];
      if (v > best) { best = v; be = e; }   // strict > = first index on tie (jnp.argmax)
    }
    eid[t] = be;
    atomicAdd(&counts[be], 1);
  }
}

// ---------------- scan: padded (x128) segment offsets ----------------
__global__ void k_scan(const int* __restrict__ counts, int* __restrict__ poff) {
  if (threadIdx.x == 0) {
    int off = 0; poff[0] = 0;
    for (int e = 0; e < EE; ++e) { off += ((counts[e] + 127) >> 7) << 7; poff[e + 1] = off; }
  }
}

// ---------------- fill rowmap: padded row -> token ----------------
__global__ void k_fillmap(const int* __restrict__ eid, const int* __restrict__ poff,
                          int* __restrict__ fill, int* __restrict__ rowmap) {
  int t = blockIdx.x * 256 + threadIdx.x;
  if (t < TOK) {
    int e = eid[t];
    int pos = atomicAdd(&fill[e], 1);
    rowmap[poff[e] + pos] = t;
  }
}

// ---------------- W [E][K][N] fp32 -> WT [E][N][K] bf16, 64x64 tiles ----------------
__global__ __launch_bounds__(256)
void k_transpose(const float* __restrict__ W, u16* __restrict__ WT, int K, int N) {
  __shared__ float tile[64][65];
  int e = blockIdx.z;
  int n0 = blockIdx.x * 64, k0 = blockIdx.y * 64;
  const float* We = W + (size_t)e * K * N;
  u16* WTe = WT + (size_t)e * K * N;
  int tx = threadIdx.x & 15, ty = threadIdx.x >> 4;   // tx: float4 column, ty: row 0..15
  #pragma unroll
  for (int i = 0; i < 4; ++i) {
    int r = ty + 16 * i;
    float4 v = *(const float4*)&We[(size_t)(k0 + r) * N + n0 + tx * 4];
    tile[r][tx * 4 + 0] = v.x; tile[r][tx * 4 + 1] = v.y;
    tile[r][tx * 4 + 2] = v.z; tile[r][tx * 4 + 3] = v.w;
  }
  __syncthreads();
  #pragma unroll
  for (int i = 0; i < 4; ++i) {
    int n = ty + 16 * i;
    ushort4 o;
    o.x = f2bf(tile[tx * 4 + 0][n]); o.y = f2bf(tile[tx * 4 + 1][n]);
    o.z = f2bf(tile[tx * 4 + 2][n]); o.w = f2bf(tile[tx * 4 + 3][n]);
    *(ushort4*)&WTe[(size_t)(n0 + n) * K + k0 + tx * 4] = o;
  }
}

// ---------------- 128x128 tile, 32x32x16 MFMA, BK=32, 3-stage pipeline ----------------
// LDS slot map (16-B chunks): slot(row,c) = (row>>3)*32 + c*8 + (row&7).
//   bank group = slot mod 8 = row&7  -> every 8-lane phase of a ds_read_b128
//   fragment read (rows r..r+31, fixed chunk) covers all 8 groups: conflict-free.
// Pipeline: stage bk+2 issued 2 iters ahead; raw s_barrier with hand vmcnt(4)
//   waits only the oldest 4 loads (this iter's tile), never the prefetch.
// G2=false: C = gather(xbf) @ W1T[e]^T, epilogue bias+gelu -> h (bf16)
// G2=true : split-K partial C = h @ W2T[e]^T -> yout + z*TOK*DD (no bias)
template <int KDIM, int NDIM, bool G2, int KSPLIT>
__global__ __launch_bounds__(256, 3)
void k_gemm(const u16* __restrict__ Abase, const u16* __restrict__ WT,
            const float* __restrict__ bias, const int* __restrict__ poff,
            const int* __restrict__ rowmap, u16* __restrict__ hout,
            float* __restrict__ yout) {
  const int mbase = blockIdx.y * 128;
  if (mbase >= poff[EE]) return;
  int e = 0;
  #pragma unroll
  for (int q = 1; q < EE; ++q) e += (mbase >= poff[q]) ? 1 : 0;
  const int nbase = blockIdx.x * 128;
  const int koff = blockIdx.z * (KDIM / KSPLIT);
  constexpr int KT = KDIM / (32 * KSPLIT);

  const int tid = threadIdx.x;
  const int w = tid >> 6, lt = tid & 63;
  const int wr = w >> 1, wc = w & 1;

  __shared__ u16 ls[3][2][4096];   // [buf][A=0/B=1][512 slots * 8 u16] = 48 KB

  // staging: wave w, gload g: lane lt -> slot = w*128 + g*64 + lt
  //   row_local = (slot>>5)*8 + (lt&7); chunk = (lt>>3)&3
  const int rl0 = (w * 4 + 0 + (lt >> 5)) * 8 + (lt & 7);
  const int rl1 = (w * 4 + 2 + (lt >> 5)) * 8 + (lt & 7);
  const int ck = (lt >> 3) & 3;
  int arow0, arow1;
  if (G2) { arow0 = mbase + rl0; arow1 = mbase + rl1; }
  else {
    arow0 = rowmap[mbase + rl0]; if (arow0 < 0) arow0 = 0;   // pad rows: garbage, never scattered
    arow1 = rowmap[mbase + rl1]; if (arow1 < 0) arow1 = 0;
  }
  const u16* gA0 = Abase + (size_t)arow0 * KDIM + koff + ck * 8;
  const u16* gA1 = Abase + (size_t)arow1 * KDIM + koff + ck * 8;
  const u16* wte = WT + (size_t)e * NDIM * KDIM + koff;
  const u16* gB0 = wte + (size_t)(nbase + rl0) * KDIM + ck * 8;
  const u16* gB1 = wte + (size_t)(nbase + rl1) * KDIM + ck * 8;

  #define STAGE(bi, ko)                                   \
    do {                                                  \
      gload16(gA0 + (ko), &ls[bi][0][(w * 128) * 8]);     \
      gload16(gA1 + (ko), &ls[bi][0][(w * 128 + 64) * 8]);\
      gload16(gB0 + (ko), &ls[bi][1][(w * 128) * 8]);     \
      gload16(gB1 + (ko), &ls[bi][1][(w * 128 + 64) * 8]);\
    } while (0)

  f32x16 acc[2][2] = {};
  STAGE(0, 0);
  STAGE(1, 32);

  int sbuf = 2, cbuf = 0;
  for (int bk = 0; bk < KT; ++bk) {
    // wait own oldest stage (4 loads) + LDS quiesce, then block barrier.
    if (bk + 1 < KT) asm volatile("s_waitcnt vmcnt(4) lgkmcnt(0)\ns_barrier" ::: "memory");
    else             asm volatile("s_waitcnt vmcnt(0) lgkmcnt(0)\ns_barrier" ::: "memory");
    if (bk + 2 < KT) STAGE(sbuf, (bk + 2) * 32);
    const u16* A = ls[cbuf][0];
    const u16* B = ls[cbuf][1];
    #pragma unroll
    for (int s = 0; s < 2; ++s) {
      const int cc = s * 2 + (lt >> 5);
      bf16x8 af[2], bg[2];
      #pragma unroll
      for (int i = 0; i < 2; ++i) {
        int r = wr * 64 + i * 32 + (lt & 31);
        int slot = ((r >> 3) << 5) + cc * 8 + (r & 7);
        af[i] = *(const bf16x8*)&A[slot * 8];
      }
      #pragma unroll
      for (int j = 0; j < 2; ++j) {
        int n = wc * 64 + j * 32 + (lt & 31);
        int slot = ((n >> 3) << 5) + cc * 8 + (n & 7);
        bg[j] = *(const bf16x8*)&B[slot * 8];
      }
      #pragma unroll
      for (int i = 0; i < 2; ++i)
        #pragma unroll
        for (int j = 0; j < 2; ++j)
          acc[i][j] = __builtin_amdgcn_mfma_f32_32x32x16_bf16(af[i], bg[j], acc[i][j], 0, 0, 0);
    }
    cbuf = (cbuf == 2) ? 0 : cbuf + 1;
    sbuf = (sbuf == 2) ? 0 : sbuf + 1;
  }
  #undef STAGE

  // ---- epilogue. 32x32 C/D layout: col = lane&31, row = (reg&3)+8*(reg>>2)+4*(lane>>5)
  if (G2) {
    float* yo = yout + (size_t)blockIdx.z * ((size_t)TOK * DD);
    #pragma unroll
    for (int i = 0; i < 2; ++i) {
      const int rbase = wr * 64 + i * 32 + 4 * (lt >> 5);
      #pragma unroll
      for (int r = 0; r < 16; ++r) {
        const int rl = rbase + (r & 3) + 8 * (r >> 2);
        int tok = rowmap[mbase + rl];
        if (tok >= 0) {
          float* yp = yo + (size_t)tok * NDIM + nbase + wc * 64 + (lt & 31);
          #pragma unroll
          for (int j = 0; j < 2; ++j) yp[j * 32] = acc[i][j][r];
        }
      }
    }
  } else {
    float bv[2];
    #pragma unroll
    for (int j = 0; j < 2; ++j)
      bv[j] = bias[(size_t)e * NDIM + nbase + wc * 64 + j * 32 + (lt & 31)];
    #pragma unroll
    for (int i = 0; i < 2; ++i) {
      const int rbase = wr * 64 + i * 32 + 4 * (lt >> 5);
      #pragma unroll
      for (int r = 0; r < 16; ++r) {
        const int rl = rbase + (r & 3) + 8 * (r >> 2);
        u16* hp = hout + (size_t)(mbase + rl) * NDIM + nbase + wc * 64 + (lt & 31);
        #pragma unroll
        for (int j = 0; j < 2; ++j) {
          float v = acc[i][j][r] + bv[j];
          v = 0.5f * v * (1.0f + erff(v * 0.70710678118654752f));   // exact gelu
          hp[j * 32] = f2bf(v);
        }
      }
    }
  }
}

// ---------------- reduce: out = b2[eid] + p0 + p1 ----------------
__global__ void k_reduce(const float* __restrict__ p0, const float* __restrict__ p1,
                         const float* __restrict__ b2, const int* __restrict__ eid,
                         float* __restrict__ out) {
  int i = blockIdx.x * 256 + threadIdx.x;   // float4 index over TOK*DD/4
  int tok = i >> 8;                          // DD/4 = 256 float4 per token
  int d4 = i & 255;
  int e = eid[tok];
  float4 b = ((const float4*)(b2 + (size_t)e * DD))[d4];
  float4 a0 = ((const float4*)p0)[i];
  float4 a1 = ((const float4*)p1)[i];
  ((float4*)out)[i] = make_float4(b.x + a0.x + a1.x, b.y + a0.y + a1.y,
                                  b.z + a0.z + a1.z, b.w + a0.w + a1.w);
}

extern "C" void kernel_launch(void* const* d_in, const int* in_sizes, int n_in,
                              void* d_out, int out_size, void* d_ws, size_t ws_size,
                              hipStream_t stream) {
  const float* x  = (const float*)d_in[0];
  const float* Wr = (const float*)d_in[1];
  const float* br = (const float*)d_in[2];
  const float* W1 = (const float*)d_in[3];
  const float* b1 = (const float*)d_in[4];
  const float* W2 = (const float*)d_in[5];
  const float* b2 = (const float*)d_in[6];
  float* out = (float*)d_out;

  char* ws = (char*)d_ws;
  int* eid    = (int*)(ws + 0);                 //   32768 B
  int* counts = (int*)(ws + 32768);             //   32 B
  int* fill   = (int*)(ws + 32768 + 64);        //   32 B
  int* poff   = (int*)(ws + 32768 + 128);       //   36 B
  int* rowmap = (int*)(ws + 33024);             //   36864 B
  u16* xbf    = (u16*)(ws + 69888);             //   16.78 MB
  u16* w1t    = (u16*)(ws + 16847104);          //   67.1 MB (dead after GEMM1 -> reused as pbuf)
  u16* w2t    = (u16*)(ws + 83955968);          //   67.1 MB
  u16* hbuf   = (u16*)(ws + 151064832);         //   75.5 MB  (total ~216 MiB)
  float* pbuf = (float*)w1t;                    //   2 x 33.55 MB split-K partials (exact fit)

  k_init<<<MAXROWS / 256, 256, 0, stream>>>(rowmap, counts, fill);
  k_route<<<TOK / 4, 256, 0, stream>>>(x, Wr, br, eid, counts, xbf);
  k_scan<<<1, 64, 0, stream>>>(counts, poff);
  k_fillmap<<<TOK / 256, 256, 0, stream>>>(eid, poff, fill, rowmap);
  k_transpose<<<dim3(HH / 64, DD / 64, EE), 256, 0, stream>>>(W1, w1t, DD, HH);
  k_transpose<<<dim3(DD / 64, HH / 64, EE), 256, 0, stream>>>(W2, w2t, HH, DD);
  k_gemm<DD, HH, false, 1><<<dim3(HH / 128, MAXMT, 1), 256, 0, stream>>>(xbf, w1t, b1, poff, rowmap, hbuf, nullptr);
  k_gemm<HH, DD, true, 2><<<dim3(DD / 128, MAXMT, 2), 256, 0, stream>>>(hbuf, w2t, nullptr, poff, rowmap, nullptr, pbuf);
  k_reduce<<<TOK * DD / 1024, 256, 0, stream>>>(pbuf, pbuf + (size_t)TOK * DD, b2, eid, out);
}

// Round 4
// 790.600 us; speedup vs baseline: 1.0036x; 1.0036x over previous
//
#include <hip/hip_runtime.h>
#include <math.h>

#define TOK   8192
#define DD    1024
#define EE    8
#define HH    4096
#define MAXROWS 9216   // 8192 + 8*128 headroom, = 72 tiles * 128
#define MAXMT 72

typedef unsigned short u16;
typedef unsigned int   u32;
typedef __bf16 bf16x8 __attribute__((ext_vector_type(8)));
typedef float  f32x16 __attribute__((ext_vector_type(16)));

__device__ __forceinline__ u16 f2bf(float f) {
  union { float f; u32 u; } v; v.f = f;
  u32 r = v.u + 0x7fffu + ((v.u >> 16) & 1u);   // RNE, finite inputs only
  return (u16)(r >> 16);
}

__device__ __forceinline__ void gload16(const void* g, void* l) {
  __builtin_amdgcn_global_load_lds(
      (const __attribute__((address_space(1))) void*)g,
      (__attribute__((address_space(3))) void*)l, 16, 0, 0);
}

// ---------------- init: rowmap=-1, zero atomic counters ----------------
__global__ void k_init(int* rowmap, int* counts, int* fill) {
  int i = blockIdx.x * 256 + threadIdx.x;
  if (i < MAXROWS) rowmap[i] = -1;
  if (blockIdx.x == 0 && threadIdx.x < EE) { counts[threadIdx.x] = 0; fill[threadIdx.x] = 0; }
}

// ---------------- routing (1 wave/token) + fused x->bf16 conversion ----------------
__global__ __launch_bounds__(256)
void k_route(const float* __restrict__ x, const float* __restrict__ Wr,
             const float* __restrict__ br, int* __restrict__ eid,
             int* __restrict__ counts, u16* __restrict__ xb) {
  int t = blockIdx.x * 4 + (threadIdx.x >> 6);
  int lt = threadIdx.x & 63;
  const float4* xr = (const float4*)(x + (size_t)t * DD);
  u16* xbr = xb + (size_t)t * DD;
  const float4* wrp = (const float4*)Wr;
  float acc[EE];
  #pragma unroll
  for (int e = 0; e < EE; ++e) acc[e] = 0.f;
  #pragma unroll
  for (int i = 0; i < 4; ++i) {
    int d4 = lt + 64 * i;          // float4 index; d = 4*d4
    float4 v = xr[d4];
    u32 p0 = (u32)f2bf(v.x) | ((u32)f2bf(v.y) << 16);
    u32 p1 = (u32)f2bf(v.z) | ((u32)f2bf(v.w) << 16);
    ((uint2*)xbr)[d4] = make_uint2(p0, p1);
    float vv[4] = { v.x, v.y, v.z, v.w };
    #pragma unroll
    for (int dd = 0; dd < 4; ++dd) {
      float xv = vv[dd];
      float4 a = wrp[(size_t)(d4 * 4 + dd) * 2];
      float4 b = wrp[(size_t)(d4 * 4 + dd) * 2 + 1];
      acc[0] += xv * a.x; acc[1] += xv * a.y; acc[2] += xv * a.z; acc[3] += xv * a.w;
      acc[4] += xv * b.x; acc[5] += xv * b.y; acc[6] += xv * b.z; acc[7] += xv * b.w;
    }
  }
  #pragma unroll
  for (int e = 0; e < EE; ++e)
    #pragma unroll
    for (int off = 32; off > 0; off >>= 1) acc[e] += __shfl_down(acc[e], off);
  if (lt == 0) {
    float best = -1e30f; int be = 0;
    #pragma unroll
    for (int e = 0; e < EE; ++e) {
      float v = acc[e] + br[e];
      if (v > best) { best = v; be = e; }   // strict > = first index on tie (jnp.argmax)
    }
    eid[t] = be;
    atomicAdd(&counts[be], 1);
  }
}

// ---------------- scan: padded (x128) segment offsets ----------------
__global__ void k_scan(const int* __restrict__ counts, int* __restrict__ poff) {
  if (threadIdx.x == 0) {
    int off = 0; poff[0] = 0;
    for (int e = 0; e < EE; ++e) { off += ((counts[e] + 127) >> 7) << 7; poff[e + 1] = off; }
  }
}

// ---------------- fill rowmap: padded row -> token ----------------
__global__ void k_fillmap(const int* __restrict__ eid, const int* __restrict__ poff,
                          int* __restrict__ fill, int* __restrict__ rowmap) {
  int t = blockIdx.x * 256 + threadIdx.x;
  if (t < TOK) {
    int e = eid[t];
    int pos = atomicAdd(&fill[e], 1);
    rowmap[poff[e] + pos] = t;
  }
}

// ---------------- W [E][K][N] fp32 -> WT [E][N][K] bf16, 64x64 tiles ----------------
__global__ __launch_bounds__(256)
void k_transpose(const float* __restrict__ W, u16* __restrict__ WT, int K, int N) {
  __shared__ float tile[64][65];
  int e = blockIdx.z;
  int n0 = blockIdx.x * 64, k0 = blockIdx.y * 64;
  const float* We = W + (size_t)e * K * N;
  u16* WTe = WT + (size_t)e * K * N;
  int tx = threadIdx.x & 15, ty = threadIdx.x >> 4;   // tx: float4 column, ty: row 0..15
  #pragma unroll
  for (int i = 0; i < 4; ++i) {
    int r = ty + 16 * i;
    float4 v = *(const float4*)&We[(size_t)(k0 + r) * N + n0 + tx * 4];
    tile[r][tx * 4 + 0] = v.x; tile[r][tx * 4 + 1] = v.y;
    tile[r][tx * 4 + 2] = v.z; tile[r][tx * 4 + 3] = v.w;
  }
  __syncthreads();
  #pragma unroll
  for (int i = 0; i < 4; ++i) {
    int n = ty + 16 * i;
    ushort4 o;
    o.x = f2bf(tile[tx * 4 + 0][n]); o.y = f2bf(tile[tx * 4 + 1][n]);
    o.z = f2bf(tile[tx * 4 + 2][n]); o.w = f2bf(tile[tx * 4 + 3][n]);
    *(ushort4*)&WTe[(size_t)(n0 + n) * K + k0 + tx * 4] = o;
  }
}

// ---------------- 128x128 tile, 32x32x16 MFMA, BK=32, double-buffered ----------------
// R2-proven loop structure (single __syncthreads per iter, compiler-managed waits)
// + R3-proven LDS slot map (16-B chunks): slot(row,c) = (row>>3)*32 + c*8 + (row&7)
//   -> bank group = row&7; every 8-lane phase of a fragment b128 covers all groups.
// Flat grid with XCD swizzle (id&7 = XCD): blocks on one XCD share n-tiles -> B stays L2-hot.
// G2=false: NT=32, C = gather(xbf) @ W1T[e]^T, epilogue bias+gelu -> h (bf16)
// G2=true : NT=8, split-K=2, partial C = h @ W2T[e]^T -> yout + z*TOK*DD (no bias)
template <int KDIM, int NDIM, bool G2>
__global__ __launch_bounds__(256, 4)
void k_gemm(const u16* __restrict__ Abase, const u16* __restrict__ WT,
            const float* __restrict__ bias, const int* __restrict__ poff,
            const int* __restrict__ rowmap, u16* __restrict__ hout,
            float* __restrict__ yout) {
  const int id = blockIdx.x;
  const int xcd = id & 7, j = id >> 3;
  int nt, mt, z;
  if (G2) { nt = xcd; mt = j >> 1; z = j & 1; }          // 8 n-tiles, KSPLIT=2
  else    { nt = xcd * 4 + (j & 3); mt = j >> 2; z = 0; } // 32 n-tiles
  const int mbase = mt * 128;
  if (mbase >= poff[EE]) return;
  int e = 0;
  #pragma unroll
  for (int q = 1; q < EE; ++q) e += (mbase >= poff[q]) ? 1 : 0;
  const int nbase = nt * 128;
  const int koff = G2 ? z * (KDIM / 2) : 0;
  const int KT = G2 ? KDIM / 64 : KDIM / 32;

  const int tid = threadIdx.x;
  const int w = tid >> 6, lt = tid & 63;
  const int wr = w >> 1, wc = w & 1;

  __shared__ u16 ls[2][2][4096];   // [buf][A/B][512 slots * 8 u16] = 32 KB

  // staging: wave w, gload g in {0,1}: lane lt -> slot = w*128 + g*64 + lt
  //   row_local = (w*4 + g*2 + (lt>>5))*8 + (lt&7); chunk = (lt>>3)&3
  const int rl0 = (w * 4 + 0 + (lt >> 5)) * 8 + (lt & 7);
  const int rl1 = (w * 4 + 2 + (lt >> 5)) * 8 + (lt & 7);
  const int ck = (lt >> 3) & 3;
  int arow0, arow1;
  if (G2) { arow0 = mbase + rl0; arow1 = mbase + rl1; }
  else {
    arow0 = rowmap[mbase + rl0]; if (arow0 < 0) arow0 = 0;   // pad rows: garbage, never scattered
    arow1 = rowmap[mbase + rl1]; if (arow1 < 0) arow1 = 0;
  }
  const u16* gA0 = Abase + (size_t)arow0 * KDIM + koff + ck * 8;
  const u16* gA1 = Abase + (size_t)arow1 * KDIM + koff + ck * 8;
  const u16* wte = WT + (size_t)e * NDIM * KDIM + koff;
  const u16* gB0 = wte + (size_t)(nbase + rl0) * KDIM + ck * 8;
  const u16* gB1 = wte + (size_t)(nbase + rl1) * KDIM + ck * 8;

  #define STAGE(bi, ko)                                   \
    do {                                                  \
      gload16(gA0 + (ko), &ls[bi][0][(w * 128) * 8]);     \
      gload16(gA1 + (ko), &ls[bi][0][(w * 128 + 64) * 8]);\
      gload16(gB0 + (ko), &ls[bi][1][(w * 128) * 8]);     \
      gload16(gB1 + (ko), &ls[bi][1][(w * 128 + 64) * 8]);\
    } while (0)

  f32x16 acc[2][2] = {};
  STAGE(0, 0);
  for (int bk = 0; bk < KT; ++bk) {
    __syncthreads();                       // drains stage bk; prev compute done before overwrite
    if (bk + 1 < KT) STAGE((bk + 1) & 1, (bk + 1) * 32);
    const u16* A = ls[bk & 1][0];
    const u16* B = ls[bk & 1][1];
    #pragma unroll
    for (int s = 0; s < 2; ++s) {
      const int cc = s * 2 + (lt >> 5);
      bf16x8 af[2], bg[2];
      #pragma unroll
      for (int i = 0; i < 2; ++i) {
        int r = wr * 64 + i * 32 + (lt & 31);
        int slot = ((r >> 3) << 5) + cc * 8 + (r & 7);
        af[i] = *(const bf16x8*)&A[slot * 8];
      }
      #pragma unroll
      for (int jj = 0; jj < 2; ++jj) {
        int n = wc * 64 + jj * 32 + (lt & 31);
        int slot = ((n >> 3) << 5) + cc * 8 + (n & 7);
        bg[jj] = *(const bf16x8*)&B[slot * 8];
      }
      #pragma unroll
      for (int i = 0; i < 2; ++i)
        #pragma unroll
        for (int jj = 0; jj < 2; ++jj)
          acc[i][jj] = __builtin_amdgcn_mfma_f32_32x32x16_bf16(af[i], bg[jj], acc[i][jj], 0, 0, 0);
    }
  }
  #undef STAGE

  // ---- epilogue. 32x32 C/D layout: col = lane&31, row = (reg&3)+8*(reg>>2)+4*(lane>>5)
  if (G2) {
    float* yo = yout + (size_t)z * ((size_t)TOK * DD);
    #pragma unroll
    for (int i = 0; i < 2; ++i) {
      const int rbase = wr * 64 + i * 32 + 4 * (lt >> 5);
      #pragma unroll
      for (int r = 0; r < 16; ++r) {
        const int rl = rbase + (r & 3) + 8 * (r >> 2);
        int tok = rowmap[mbase + rl];
        if (tok >= 0) {
          float* yp = yo + (size_t)tok * NDIM + nbase + wc * 64 + (lt & 31);
          #pragma unroll
          for (int jj = 0; jj < 2; ++jj) yp[jj * 32] = acc[i][jj][r];
        }
      }
    }
  } else {
    float bv[2];
    #pragma unroll
    for (int jj = 0; jj < 2; ++jj)
      bv[jj] = bias[(size_t)e * NDIM + nbase + wc * 64 + jj * 32 + (lt & 31)];
    #pragma unroll
    for (int i = 0; i < 2; ++i) {
      const int rbase = wr * 64 + i * 32 + 4 * (lt >> 5);
      #pragma unroll
      for (int r = 0; r < 16; ++r) {
        const int rl = rbase + (r & 3) + 8 * (r >> 2);
        u16* hp = hout + (size_t)(mbase + rl) * NDIM + nbase + wc * 64 + (lt & 31);
        #pragma unroll
        for (int jj = 0; jj < 2; ++jj) {
          float v = acc[i][jj][r] + bv[jj];
          v = 0.5f * v * (1.0f + erff(v * 0.70710678118654752f));   // exact gelu
          hp[jj * 32] = f2bf(v);
        }
      }
    }
  }
}

// ---------------- reduce: out = b2[eid] + p0 + p1 ----------------
__global__ void k_reduce(const float* __restrict__ p0, const float* __restrict__ p1,
                         const float* __restrict__ b2, const int* __restrict__ eid,
                         float* __restrict__ out) {
  int i = blockIdx.x * 256 + threadIdx.x;   // float4 index over TOK*DD/4
  int tok = i >> 8;                          // DD/4 = 256 float4 per token
  int d4 = i & 255;
  int e = eid[tok];
  float4 b = ((const float4*)(b2 + (size_t)e * DD))[d4];
  float4 a0 = ((const float4*)p0)[i];
  float4 a1 = ((const float4*)p1)[i];
  ((float4*)out)[i] = make_float4(b.x + a0.x + a1.x, b.y + a0.y + a1.y,
                                  b.z + a0.z + a1.z, b.w + a0.w + a1.w);
}

extern "C" void kernel_launch(void* const* d_in, const int* in_sizes, int n_in,
                              void* d_out, int out_size, void* d_ws, size_t ws_size,
                              hipStream_t stream) {
  const float* x  = (const float*)d_in[0];
  const float* Wr = (const float*)d_in[1];
  const float* br = (const float*)d_in[2];
  const float* W1 = (const float*)d_in[3];
  const float* b1 = (const float*)d_in[4];
  const float* W2 = (const float*)d_in[5];
  const float* b2 = (const float*)d_in[6];
  float* out = (float*)d_out;

  char* ws = (char*)d_ws;
  int* eid    = (int*)(ws + 0);                 //   32768 B
  int* counts = (int*)(ws + 32768);             //   32 B
  int* fill   = (int*)(ws + 32768 + 64);        //   32 B
  int* poff   = (int*)(ws + 32768 + 128);       //   36 B
  int* rowmap = (int*)(ws + 33024);             //   36864 B
  u16* xbf    = (u16*)(ws + 69888);             //   16.78 MB
  u16* w1t    = (u16*)(ws + 16847104);          //   64 MiB (dead after GEMM1 -> pbuf)
  u16* w2t    = (u16*)(ws + 83955968);          //   64 MiB
  u16* hbuf   = (u16*)(ws + 151064832);         //   72 MiB  (total ~216 MiB)
  float* pbuf = (float*)w1t;                    //   2 x 32 MiB split-K partials (exact fit)

  k_init<<<MAXROWS / 256, 256, 0, stream>>>(rowmap, counts, fill);
  k_route<<<TOK / 4, 256, 0, stream>>>(x, Wr, br, eid, counts, xbf);
  k_scan<<<1, 64, 0, stream>>>(counts, poff);
  k_fillmap<<<TOK / 256, 256, 0, stream>>>(eid, poff, fill, rowmap);
  k_transpose<<<dim3(HH / 64, DD / 64, EE), 256, 0, stream>>>(W1, w1t, DD, HH);
  k_transpose<<<dim3(DD / 64, HH / 64, EE), 256, 0, stream>>>(W2, w2t, HH, DD);
  k_gemm<DD, HH, false><<<32 * MAXMT, 256, 0, stream>>>(xbf, w1t, b1, poff, rowmap, hbuf, nullptr);
  k_gemm<HH, DD, true><<<8 * MAXMT * 2, 256, 0, stream>>>(hbuf, w2t, nullptr, poff, rowmap, nullptr, pbuf);
  k_reduce<<<TOK * DD / 1024, 256, 0, stream>>>(pbuf, pbuf + (size_t)TOK * DD, b2, eid, out);
}